// Round 1
// baseline (212.573 us; speedup 1.0000x reference)
//
#include <hip/hip_runtime.h>

// SequenceGroupAggregating: out[b,a,:] = mean_{s: group_by[b,s]==a} x[b,s,:]
// group_by sorted along S -> each group is a contiguous segment; consecutive
// groups' segments are adjacent, so a block owning AG consecutive groups
// owns ONE contiguous row range [ends[a0-1], ends[a0+AG-1]).
//
// Phase 1: one thread per (b,a) does a single upper_bound binary search
//          (segment start == previous group's end; no starts stored).
// Phase 2: one block per (AG consecutive groups, b). The block streams its
//          contiguous row span in a single loop with 1-deep prefetch (the
//          compiler sustains >=2 outstanding loads via vmcnt(1)), flushing a
//          group with a uniform scalar branch when s+1 hits its end. Empty
//          groups (end==prev end) flush with cnt=0 -> scale 0 -> zero row.
//          Nontemporal loads (x read once) + nontemporal stores (out written
//          once, never re-read) keep the 64 MB output stream from
//          write-allocating against the 128 MB read stream.
// Floor: 192 MB ~= 33-36 us at 5.4-6.3 TB/s.

constexpr int AG = 4;  // consecutive groups per block (A % AG == 0)

typedef float v4f __attribute__((ext_vector_type(4)));

__global__ __launch_bounds__(256) void seg_ends_kernel(
    const int* __restrict__ gb,    // (B, S) sorted along S
    int*       __restrict__ ends,  // (B, A): upper_bound(g, a) == segment end
    int S, int A) {
  const int b = blockIdx.y;
  const int a = blockIdx.x * blockDim.x + threadIdx.x;
  if (a >= A) return;
  const int* __restrict__ g = gb + (size_t)b * S;
  int lo = 0, hi = S;
  while (lo < hi) { int m = (lo + hi) >> 1; if (g[m] <= a) lo = m + 1; else hi = m; }
  ends[(size_t)b * A + a] = lo;
}

__global__ __launch_bounds__(256) void seq_group_agg_kernel(
    const float* __restrict__ x,     // (B, S, H)
    const int*   __restrict__ ends,  // (B, A)
    float*       __restrict__ out,   // (B, A, H)
    int S, int H4, int A) {
  const int b  = blockIdx.y;
  const int a0 = blockIdx.x * AG;

  // Block-uniform group ends: e[0] = span start, e[1..AG] = group ends.
  __shared__ int e[AG + 1];
  if (threadIdx.x <= AG) {
    const int idx = a0 - 1 + (int)threadIdx.x;
    e[threadIdx.x] = (idx < 0) ? 0 : ends[(size_t)b * A + idx];
  }
  __syncthreads();

  const int h4 = threadIdx.x;  // H4 == blockDim.x == 256
  const v4f* __restrict__ xb = (const v4f*)x + (size_t)b * S * H4 + h4;
  v4f* __restrict__ ob = (v4f*)out + ((size_t)b * A + a0) * H4 + h4;

  const int sBeg = e[0];
  const int sEnd = e[AG];

  int j = 0;
  int y = e[1];
  int seg_start = sBeg;

  // Leading empty groups (also covers an entirely-empty span).
  while (j < AG && y == sBeg) {
    __builtin_nontemporal_store((v4f)(0.0f), ob + (size_t)j * H4);
    ++j;
    y = (j < AG) ? e[j + 1] : -1;
  }

  // Single streaming pass over the contiguous span with 1-deep prefetch.
  v4f acc = (v4f)(0.0f);
  v4f nxt = (v4f)(0.0f);
  if (sBeg < sEnd) nxt = __builtin_nontemporal_load(xb + (size_t)sBeg * H4);
  for (int s = sBeg; s < sEnd; ++s) {
    const v4f cur = nxt;
    if (s + 1 < sEnd) nxt = __builtin_nontemporal_load(xb + (size_t)(s + 1) * H4);
    acc += cur;
    // Uniform flush: group j ends at s+1 (runs handle empty groups, cnt==0).
    while (j < AG && s + 1 == y) {
      const int cnt = y - seg_start;
      const float sc = (cnt > 0) ? 1.0f / (float)cnt : 0.0f;
      __builtin_nontemporal_store(acc * sc, ob + (size_t)j * H4);
      acc = (v4f)(0.0f);
      seg_start = y;
      ++j;
      y = (j < AG) ? e[j + 1] : -1;
    }
  }
}

extern "C" void kernel_launch(void* const* d_in, const int* in_sizes, int n_in,
                              void* d_out, int out_size, void* d_ws, size_t ws_size,
                              hipStream_t stream) {
  const float* x  = (const float*)d_in[0];
  const int*   gb = (const int*)d_in[1];
  float*       out = (float*)d_out;

  const int BS = in_sizes[1];        // B*S = 32768
  const int H  = in_sizes[0] / BS;   // 1024
  const int A  = 1024;               // agg_step (fixed by setup_inputs)
  const int B  = (out_size / H) / A; // 16
  const int S  = BS / B;             // 2048

  int* ends = (int*)d_ws;            // B*A*4 = 64 KB scratch

  dim3 g1((A + 255) / 256, B);
  seg_ends_kernel<<<g1, 256, 0, stream>>>(gb, ends, S, A);

  dim3 g2(A / AG, B);
  seq_group_agg_kernel<<<g2, 256, 0, stream>>>(x, ends, out, S, H / 4, A);
}